// Round 19
// baseline (326.765 us; speedup 1.0000x reference)
//
#include <hip/hip_runtime.h>
#include <hip/hip_cooperative_groups.h>

namespace cg = cooperative_groups;

#define N_NODES 10000
#define N_EDGES 160000
#define E_TOT   170000   // + self loops
#define H1      8
#define C1      120
#define F1      960      // H1*C1
#define BSTRIDE 64       // bucket slots per node (max in-degree ~45 << 64)

typedef _Float16 h2 __attribute__((ext_vector_type(2)));
typedef _Float16 f16x8 __attribute__((ext_vector_type(8)));
typedef float f32x4 __attribute__((ext_vector_type(4)));
union H2U { unsigned u; h2 h; };
union AU  { uint4 u; f16x8 h; };

#if defined(__has_builtin)
#if __has_builtin(__builtin_amdgcn_fdot2)
#define FDOT2(a,b,c) __builtin_amdgcn_fdot2((a),(b),(c),false)
#endif
#endif
#ifndef FDOT2
#define FDOT2(a,b,c) ((float)(a)[0]*(float)(b)[0] + (float)(a)[1]*(float)(b)[1] + (c))
#endif

__device__ __forceinline__ float lrelu(float v) { return fmaxf(v, 0.2f * v); }
__device__ __forceinline__ unsigned packh2(float a, float b) {
    H2U u; u.h = (h2){(_Float16)a, (_Float16)b}; return u.u;
}
__device__ __forceinline__ h2 toh2(unsigned v) { H2U u; u.u = v; return u.h; }

struct MegaParams {
    const float* x; const int* ei;
    const float *W1l, *W1r, *b1l, *b1r, *att1, *bias1, *W2l, *W2r, *b2l, *b2r, *att2, *bias2;
    float* out;
    uint4* BpH; int* Bh; uint2* WAh; unsigned* PBh; uint4* W2P;
    uint2* xh; float *Ls, *Lr;
    int *cnt, *elist, *slist;
    float *e1, *xl2, *xr2;
};

#define AGG(hi, wv) { float W_ = (wv); ssum[hi] += W_; ag[hi].x += W_*xv.x; ag[hi].y += W_*xv.y; ag[hi].z += W_*xv.z; ag[hi].w += W_*xv.w; }

// One cooperative kernel: phase0 prep -> sync -> phase1 logits+fill -> sync ->
// phase2 agg1+transform2 -> sync -> phase3 attn2. Bodies are verbatim ports of
// the R18 kernels (grid-stride over virtual blocks; no early returns).
__global__ __launch_bounds__(256, 4) void mega(MegaParams p) {
    cg::grid_group grid = cg::this_grid();
    const int tid = threadIdx.x;
    const int bid = blockIdx.x;
    const int G   = gridDim.x;

    __shared__ uint4 BpL[2048];   // 32 KB (phase 1)
    __shared__ float Pp[3][72];   // phase 0 node blocks
    __shared__ float Ps[72];

    // ================= phase 0: prep =================
    for (int vb = bid; vb < 84; vb += G) {
        if (vb < 4) {
            // zero this vb's Bp range (512 uint4), then write sorted |att|-folded table
            p.BpH[vb*512 + tid]       = make_uint4(0u,0u,0u,0u);
            p.BpH[vb*512 + 256 + tid] = make_uint4(0u,0u,0u,0u);
            __syncthreads();
            if (tid < 240) {
                int rc = vb * 240 + tid;
                int h = rc / C1, u = rc - h * C1;
                float a = p.att1[rc];
                int cntPos = 0, rankB = 0;
                for (int v = 0; v < C1; ++v) {
                    bool pos = p.att1[h*C1 + v] > 0.f;
                    cntPos += pos ? 1 : 0;
                    rankB  += (v < u && pos) ? 1 : 0;
                }
                int newu = (a > 0.f) ? rankB : (cntPos + (u - rankB));
                float sc = fabsf(0.4f * a);
                float wl0 = p.W1l[rc], wl1 = p.W1l[F1+rc], wl2 = p.W1l[2*F1+rc], wl3 = p.W1l[3*F1+rc];
                float wr0 = p.W1r[rc], wr1 = p.W1r[F1+rc], wr2 = p.W1r[2*F1+rc], wr3 = p.W1r[3*F1+rc];
                float bc = p.b1l[rc] + p.b1r[rc];
                int pc2 = h * 128 + newu;
                int ct = pc2 >> 4, cl2 = pc2 & 15;
                p.BpH[ct*32 + cl2] = make_uint4(packh2(sc*wl0, sc*wl1), packh2(sc*wl2, sc*wl3),
                                                packh2(sc*wr0, sc*wr1), packh2(sc*wr2, sc*wr3));
                p.BpH[ct*32 + 16 + cl2] = make_uint4(packh2(sc*bc, 0.f), 0u, 0u, 0u);
                if (u == 0) p.Bh[h] = cntPos;
                p.WAh[rc] = make_uint2(packh2(wl0, wl1), packh2(wl2, wl3));
                p.PBh[rc] = packh2(p.b1l[rc], p.bias1[rc]);
            }
            if (tid < 120) {
                int i = vb * 120 + tid;       // pair index: h = i/60, u = i%60
                int h = i / 60, u = i - h * 60;
                int c0 = h * C1 + u, c1 = c0 + 60;
                const float4 wl0 = ((const float4*)p.W2l)[c0], wl1 = ((const float4*)p.W2l)[c1];
                const float4 wr0 = ((const float4*)p.W2r)[c0], wr1 = ((const float4*)p.W2r)[c1];
                p.W2P[i*2]   = make_uint4(packh2(wl0.x, wl1.x), packh2(wl0.y, wl1.y),
                                          packh2(wl0.z, wl1.z), packh2(wl0.w, wl1.w));
                p.W2P[i*2+1] = make_uint4(packh2(wr0.x, wr1.x), packh2(wr0.y, wr1.y),
                                          packh2(wr0.z, wr1.z), packh2(wr0.w, wr1.w));
            }
        } else if (vb < 44) {
            // Ps via 3-way parallel partials, then 250 nodes: xh pack, Ls, Lr
            {
                int o = tid % 72, pp = tid / 72;
                if (tid < 216) {
                    int h = o / 9, j = o % 9;
                    float acc = 0.f;
                    int u0 = pp * 40;
                    for (int u = u0; u < u0 + 40; ++u) {
                        int c = h * C1 + u;
                        float a = p.att1[c];
                        float w;
                        if (j < 4)      w = p.W1l[j * F1 + c];
                        else if (j < 8) w = p.W1r[(j - 4) * F1 + c];
                        else            w = p.b1l[c] + p.b1r[c];
                        acc = fmaf(a, w, acc);
                    }
                    Pp[pp][o] = acc;
                }
            }
            __syncthreads();
            if (tid < 72) Ps[tid] = 0.6f * (Pp[0][tid] + Pp[1][tid] + Pp[2][tid]);
            __syncthreads();
            int n = (vb - 4) * 250 + tid;
            if (tid < 250) {
                float4 xv = ((const float4*)p.x)[n];
                p.xh[n] = make_uint2(packh2(xv.x, xv.y), packh2(xv.z, xv.w));
#pragma unroll
                for (int h = 0; h < H1; ++h) {
                    const float* pp2 = Ps + h * 9;
                    p.Ls[n*8+h] = xv.x*pp2[0] + xv.y*pp2[1] + xv.z*pp2[2] + xv.w*pp2[3];
                    p.Lr[n*8+h] = xv.x*pp2[4] + xv.y*pp2[5] + xv.z*pp2[6] + xv.w*pp2[7] + pp2[8];
                }
            }
            __syncthreads();   // Ps reused if another vb lands on this block
        } else {
            int i = (vb - 44) * 256 + tid;
            if (i < N_NODES) p.cnt[i] = 0;
        }
    }
    grid.sync();

    // ================= phase 1: logits + bucket fill =================
    for (int i = tid; i < 2048; i += 256) BpL[i] = p.BpH[i];
    for (int ef = bid * 256 + tid; ef < E_TOT; ef += G * 256) {
        int s, d;
        if (ef < N_EDGES) { s = p.ei[ef]; d = p.ei[N_EDGES + ef]; }
        else { s = ef - N_EDGES; d = s; }
        int pos = atomicAdd(&p.cnt[d], 1);
        int slot = d * BSTRIDE + pos;
        p.elist[slot] = ef;
        p.slist[slot] = s;
    }
    __syncthreads();

    {
        const int lane = tid & 63;
        const int cl = lane & 15, g = lane >> 4;
        const int g4 = g * 4;
        const int nunits = (E_TOT + 127) / 128;   // 4 waves x 32 edges per unit
        for (int vb = bid; vb < nunits; vb += G) {
            int ebase = vb * 128 + (tid >> 6) * 32;
            if (ebase >= E_TOT) continue;

            int s0 = 0, d0 = 0, s1 = 0, d1 = 0;
            AU zu0, zu1;
            zu0.u = zu1.u = make_uint4(0u,0u,0u,0u);
            if (g == 0) {
                {
                    int er = ebase + cl;
                    if (er >= E_TOT) er = E_TOT - 1;
                    if (er < N_EDGES) { s0 = p.ei[er]; d0 = p.ei[N_EDGES + er]; }
                    else { s0 = er - N_EDGES; d0 = s0; }
                    uint2 a = p.xh[s0], bb = p.xh[d0];
                    zu0.u = make_uint4(a.x, a.y, bb.x, bb.y);
                }
                {
                    int er = ebase + 16 + cl;
                    if (er >= E_TOT) er = E_TOT - 1;
                    if (er < N_EDGES) { s1 = p.ei[er]; d1 = p.ei[N_EDGES + er]; }
                    else { s1 = er - N_EDGES; d1 = s1; }
                    uint2 a = p.xh[s1], bb = p.xh[d1];
                    zu1.u = make_uint4(a.x, a.y, bb.x, bb.y);
                }
            } else if (g == 1) {
                uint4 v = make_uint4(0x00003C00u, 0u, 0u, 0u);   // k8 = 1.0 (bias row)
                zu0.u = zu1.u = v;
            }
            int s0a = __shfl(s0, cl, 64), d0a = __shfl(d0, cl, 64);
            int s1a = __shfl(s1, cl, 64), d1a = __shfl(d1, cl, 64);
            float2 ls0 = *(const float2*)(p.Ls + s0a*8 + 2*g);
            float2 lr0 = *(const float2*)(p.Lr + d0a*8 + 2*g);
            float2 ls1 = *(const float2*)(p.Ls + s1a*8 + 2*g);
            float2 lr1 = *(const float2*)(p.Lr + d1a*8 + 2*g);

            float kA0 = 0.f, kA1 = 0.f, kB0 = 0.f, kB1 = 0.f;
#pragma unroll
            for (int h = 0; h < H1; ++h) {
                int bh = p.Bh[h];
                float aa0 = 0.f, aa1 = 0.f;
#pragma unroll
                for (int tt = 0; tt < 8; ++tt) {
                    int ct = h * 8 + tt;
                    AU wu;
                    wu.u = make_uint4(0u,0u,0u,0u);
                    if (lane < 32) wu.u = BpL[ct*32 + lane];
                    f32x4 z = {0.f, 0.f, 0.f, 0.f};
                    f32x4 dd0 = __builtin_amdgcn_mfma_f32_16x16x32_f16(wu.h, zu0.h, z, 0, 0, 0);
                    f32x4 dd1 = __builtin_amdgcn_mfma_f32_16x16x32_f16(wu.h, zu1.h, z, 0, 0, 0);
#pragma unroll
                    for (int r = 0; r < 4; ++r) {
                        float sel = ((tt*16 + r) + g4 < bh) ? 1.f : -1.f;
                        aa0 = fmaf(sel, fabsf(dd0[r]), aa0);
                        aa1 = fmaf(sel, fabsf(dd1[r]), aa1);
                    }
                }
                aa0 += __shfl_xor(aa0, 16, 64); aa0 += __shfl_xor(aa0, 32, 64);
                aa1 += __shfl_xor(aa1, 16, 64); aa1 += __shfl_xor(aa1, 32, 64);
                bool pk = (g == (h >> 1));
                if (h & 1) { kA1 = pk ? aa0 : kA1; kB1 = pk ? aa1 : kB1; }
                else       { kA0 = pk ? aa0 : kA0; kB0 = pk ? aa1 : kB0; }
            }

            {
                int e0 = ebase + cl;
                if (e0 < E_TOT) {
                    float2 o = make_float2(__expf(ls0.x + lr0.x + kA0), __expf(ls0.y + lr0.y + kA1));
                    *(float2*)(p.e1 + (size_t)e0*8 + 2*g) = o;
                }
            }
            {
                int e1i = ebase + 16 + cl;
                if (e1i < E_TOT) {
                    float2 o = make_float2(__expf(ls1.x + lr1.x + kB0), __expf(ls1.y + lr1.y + kB1));
                    *(float2*)(p.e1 + (size_t)e1i*8 + 2*g) = o;
                }
            }
        }
    }
    grid.sync();

    // ================= phase 2: agg1 + expand + relu + transform2 =================
    {
        const int l = tid & 15;
        for (int vb = bid; vb < N_NODES / 16; vb += G) {
            int node = vb * 16 + (tid >> 4);
            int beg = node * BSTRIDE, end = beg + p.cnt[node];

            float ssum[H1]; float4 ag[H1];
#pragma unroll
            for (int h = 0; h < H1; ++h) { ssum[h] = 0.f; ag[h] = make_float4(0.f,0.f,0.f,0.f); }

            for (int i = beg + l; i < end; i += 16) {
                int e = p.elist[i];
                const float4* pe = (const float4*)(p.e1 + (size_t)e * 8);
                float4 wa = pe[0], wb = pe[1];
                float4 xv = ((const float4*)p.x)[p.slist[i]];
                AGG(0, wa.x) AGG(1, wa.y) AGG(2, wa.z) AGG(3, wa.w)
                AGG(4, wb.x) AGG(5, wb.y) AGG(6, wb.z) AGG(7, wb.w)
            }
#pragma unroll
            for (int off = 8; off; off >>= 1) {
#pragma unroll
                for (int h = 0; h < H1; ++h) {
                    ssum[h] += __shfl_xor(ssum[h], off, 64);
                    ag[h].x += __shfl_xor(ag[h].x, off, 64);
                    ag[h].y += __shfl_xor(ag[h].y, off, 64);
                    ag[h].z += __shfl_xor(ag[h].z, off, 64);
                    ag[h].w += __shfl_xor(ag[h].w, off, 64);
                }
            }
            unsigned agA[H1], agB[H1], sg[H1];
#pragma unroll
            for (int h = 0; h < H1; ++h) {
                float inv = 1.f / (ssum[h] + 1e-16f);
                agA[h] = packh2(ag[h].x * inv, ag[h].y * inv);
                agB[h] = packh2(ag[h].z * inv, ag[h].w * inv);
                sg[h]  = packh2(ssum[h] * inv, 1.f);
            }

            float al0=0, al1=0, al2=0, al3=0, ar0=0, ar1=0, ar2=0, ar3=0;
#pragma unroll
            for (int h = 0; h < H1; ++h) {
                h2 ga = toh2(agA[h]), gb = toh2(agB[h]), gs = toh2(sg[h]);
#pragma unroll
                for (int j = 0; j < 4; ++j) {
                    int u = l + 16*j;
                    if (u < 60) {
                        int c0 = h*C1 + u;
                        uint2 wa0 = p.WAh[c0];      unsigned pb0 = p.PBh[c0];
                        uint2 wa1 = p.WAh[c0 + 60]; unsigned pb1 = p.PBh[c0 + 60];
                        float f0 = FDOT2(gs, toh2(pb0), 0.f);
                        f0 = FDOT2(ga, toh2(wa0.x), f0);
                        f0 = FDOT2(gb, toh2(wa0.y), f0);
                        f0 = fmaxf(f0, 0.f);
                        float f1 = FDOT2(gs, toh2(pb1), 0.f);
                        f1 = FDOT2(ga, toh2(wa1.x), f1);
                        f1 = FDOT2(gb, toh2(wa1.y), f1);
                        f1 = fmaxf(f1, 0.f);
                        h2 hp = toh2(packh2(f0, f1));
                        int pi = (h*60 + u) * 2;
                        uint4 wA = p.W2P[pi], wB = p.W2P[pi + 1];
                        al0 = FDOT2(hp, toh2(wA.x), al0); al1 = FDOT2(hp, toh2(wA.y), al1);
                        al2 = FDOT2(hp, toh2(wA.z), al2); al3 = FDOT2(hp, toh2(wA.w), al3);
                        ar0 = FDOT2(hp, toh2(wB.x), ar0); ar1 = FDOT2(hp, toh2(wB.y), ar1);
                        ar2 = FDOT2(hp, toh2(wB.z), ar2); ar3 = FDOT2(hp, toh2(wB.w), ar3);
                    }
                }
            }
#pragma unroll
            for (int off = 8; off; off >>= 1) {
                al0 += __shfl_xor(al0, off, 64); al1 += __shfl_xor(al1, off, 64);
                al2 += __shfl_xor(al2, off, 64); al3 += __shfl_xor(al3, off, 64);
                ar0 += __shfl_xor(ar0, off, 64); ar1 += __shfl_xor(ar1, off, 64);
                ar2 += __shfl_xor(ar2, off, 64); ar3 += __shfl_xor(ar3, off, 64);
            }
            if (l == 0) {
                ((float4*)p.xl2)[node] = make_float4(al0 + p.b2l[0], al1 + p.b2l[1], al2 + p.b2l[2], al3 + p.b2l[3]);
                ((float4*)p.xr2)[node] = make_float4(ar0 + p.b2r[0], ar1 + p.b2r[1], ar2 + p.b2r[2], ar3 + p.b2r[3]);
            }
        }
    }
    grid.sync();

    // ================= phase 3: attn2 =================
    {
        const int l = tid & 15;
        float a0 = p.att2[0], a1 = p.att2[1], a2 = p.att2[2], a3 = p.att2[3];
        for (int vb = bid; vb < N_NODES / 16; vb += G) {
            int node = vb * 16 + (tid >> 4);
            int beg = node * BSTRIDE, end = beg + p.cnt[node];
            float4 xr = ((const float4*)p.xr2)[node];

            float ssum = 0.f;
            float4 acc = make_float4(0.f, 0.f, 0.f, 0.f);
            for (int i = beg + l; i < end; i += 16) {
                float4 v = ((const float4*)p.xl2)[p.slist[i]];
                float lg = a0*lrelu(v.x + xr.x) + a1*lrelu(v.y + xr.y)
                         + a2*lrelu(v.z + xr.z) + a3*lrelu(v.w + xr.w);
                float w = __expf(lg);
                ssum += w;
                acc.x += w*v.x; acc.y += w*v.y; acc.z += w*v.z; acc.w += w*v.w;
            }
#pragma unroll
            for (int off = 8; off; off >>= 1) {
                ssum  += __shfl_xor(ssum,  off, 64);
                acc.x += __shfl_xor(acc.x, off, 64);
                acc.y += __shfl_xor(acc.y, off, 64);
                acc.z += __shfl_xor(acc.z, off, 64);
                acc.w += __shfl_xor(acc.w, off, 64);
            }
            if (l == 0) {
                float inv = 1.f / (ssum + 1e-16f);
                ((float4*)p.out)[node] = make_float4(acc.x*inv + p.bias2[0], acc.y*inv + p.bias2[1],
                                                     acc.z*inv + p.bias2[2], acc.w*inv + p.bias2[3]);
            }
        }
    }
}

extern "C" void kernel_launch(void* const* d_in, const int* in_sizes, int n_in,
                              void* d_out, int out_size, void* d_ws, size_t ws_size,
                              hipStream_t stream) {
    MegaParams mp;
    mp.x     = (const float*)d_in[0];
    mp.ei    = (const int*)  d_in[1];
    mp.W1l   = (const float*)d_in[2];
    mp.W1r   = (const float*)d_in[3];
    mp.b1l   = (const float*)d_in[4];
    mp.b1r   = (const float*)d_in[5];
    mp.att1  = (const float*)d_in[6];
    mp.bias1 = (const float*)d_in[7];
    mp.W2l   = (const float*)d_in[8];
    mp.W2r   = (const float*)d_in[9];
    mp.b2l   = (const float*)d_in[10];
    mp.b2r   = (const float*)d_in[11];
    mp.att2  = (const float*)d_in[12];
    mp.bias2 = (const float*)d_in[13];
    mp.out   = (float*)d_out;

    // workspace carve-up (segments 16B-aligned)
    float* e1   = (float*)d_ws;                   // E_TOT*8 = 1,360,000 f (EDGE order)
    float* Ls   = e1 + (size_t)E_TOT * 8;         // 80,000
    float* Lr   = Ls + 80000;                     // 80,000
    float* xl2  = Lr + 80000;                     // 40,000
    float* xr2  = xl2 + 40000;                    // 40,000
    unsigned* BpHu = (unsigned*)(xr2 + 40000);    // 8,192 (uint4[2048])
    int* Bh     = (int*)(BpHu + 8192);            // 16 (8 used)
    unsigned* WAhu = (unsigned*)(Bh + 16);        // 1,920 (uint2[960])
    unsigned* W2Pu = WAhu + 1920;                 // 7,680 (uint4[1920])
    unsigned* PBhu = W2Pu + 7680;                 // 960
    unsigned* xhu  = PBhu + 960;                  // 20,000 (uint2[10000])
    int* cnt    = (int*)(xhu + 20000);            // 10,000
    int* elist  = cnt + 10000;                    // N_NODES*BSTRIDE = 640,000
    int* slist  = elist + N_NODES * BSTRIDE;      // 640,000

    mp.e1 = e1; mp.Ls = Ls; mp.Lr = Lr; mp.xl2 = xl2; mp.xr2 = xr2;
    mp.BpH = (uint4*)BpHu; mp.Bh = Bh; mp.WAh = (uint2*)WAhu;
    mp.PBh = PBhu; mp.W2P = (uint4*)W2Pu; mp.xh = (uint2*)xhu;
    mp.cnt = cnt; mp.elist = elist; mp.slist = slist;

    // cooperative grid sizing: co-resident capacity, clamped to max unit count
    int maxPerCU = 0;
    if (hipOccupancyMaxActiveBlocksPerMultiprocessor(&maxPerCU, mega, 256, 0) != hipSuccess || maxPerCU <= 0)
        maxPerCU = 2;
    int dev = 0;
    hipGetDevice(&dev);
    int numCU = 0;
    if (hipDeviceGetAttribute(&numCU, hipDeviceAttributeMultiprocessorCount, dev) != hipSuccess || numCU <= 0)
        numCU = 256;
    long long Gl = (long long)maxPerCU * numCU;
    const int maxUnits = (E_TOT + 127) / 128;   // 1329, largest phase
    int G = (int)(Gl > maxUnits ? maxUnits : Gl);
    if (G < 1) G = 1;

    void* args[] = { &mp };
    hipLaunchCooperativeKernel(mega, dim3(G), dim3(256), args, 0, stream);
}

// Round 20
// 69.010 us; speedup vs baseline: 4.7351x; 4.7351x over previous
//
#include <hip/hip_runtime.h>

#define N_NODES 10000
#define N_EDGES 160000
#define E_TOT   170000   // + self loops
#define H1      8
#define C1      120
#define F1      960      // H1*C1
#define BSTRIDE 64       // bucket slots per node (max in-degree ~45 << 64)

typedef _Float16 h2 __attribute__((ext_vector_type(2)));
typedef _Float16 f16x8 __attribute__((ext_vector_type(8)));
typedef float f32x4 __attribute__((ext_vector_type(4)));
typedef float f32x16 __attribute__((ext_vector_type(16)));
union H2U { unsigned u; h2 h; };
union AU  { uint4 u; f16x8 h; };

#if defined(__has_builtin)
#if __has_builtin(__builtin_amdgcn_fdot2)
#define FDOT2(a,b,c) __builtin_amdgcn_fdot2((a),(b),(c),false)
#endif
#endif
#ifndef FDOT2
#define FDOT2(a,b,c) ((float)(a)[0]*(float)(b)[0] + (float)(a)[1]*(float)(b)[1] + (c))
#endif

__device__ __forceinline__ float lrelu(float v) { return fmaxf(v, 0.2f * v); }
__device__ __forceinline__ unsigned packh2(float a, float b) {
    H2U u; u.h = (h2){(_Float16)a, (_Float16)b}; return u.u;
}
__device__ __forceinline__ h2 toh2(unsigned v) { H2U u; u.u = v; return u.h; }

// ---------------- fused prep ----------------
// blocks 0..3: zero own Bp range; t<240: |0.4*att|-folded sorted weight table
//   in 32x32-tile layout: pc2 = h*128+newu, ct = pc2>>5, cl = pc2&31;
//   weights at BpH[ct*64+cl], bias row (k8) at BpH[ct*64+32+cl]; Bh[h]=#pos.
//   WAh/PBh (orig order); W2P (t<120).
// blocks 4..43: Ps 3-way-parallel; 250 nodes each: xh pack, Ls, Lr.
// blocks 44..83: zero cnt.
__global__ __launch_bounds__(256) void prep(
        const float* __restrict__ x,
        const float* __restrict__ W1l, const float* __restrict__ W1r,
        const float* __restrict__ b1l, const float* __restrict__ b1r,
        const float* __restrict__ att1, const float* __restrict__ bias1,
        const float* __restrict__ W2l, const float* __restrict__ W2r,
        uint4* __restrict__ BpH, int* __restrict__ Bh,
        uint2* __restrict__ WAh, unsigned* __restrict__ PBh,
        uint4* __restrict__ W2P,
        uint2* __restrict__ xh, float* __restrict__ Ls, float* __restrict__ Lr,
        int* __restrict__ cnt) {
    int b = blockIdx.x, t = threadIdx.x;
    if (b >= 44) {
        int i = (b - 44) * 256 + t;
        if (i < N_NODES) cnt[i] = 0;
        return;
    }
    if (b < 4) {
        // phase 0: zero this block's Bp range (512 uint4)
        BpH[b*512 + t]       = make_uint4(0u,0u,0u,0u);
        BpH[b*512 + 256 + t] = make_uint4(0u,0u,0u,0u);
        __syncthreads();
        if (t < 240) {
            int rc = b * 240 + t;
            int h = rc / C1, u = rc - h * C1;
            float a = att1[rc];
            int cntPos = 0, rankB = 0;
            for (int v = 0; v < C1; ++v) {
                bool pos = att1[h*C1 + v] > 0.f;
                cntPos += pos ? 1 : 0;
                rankB  += (v < u && pos) ? 1 : 0;
            }
            int newu = (a > 0.f) ? rankB : (cntPos + (u - rankB));
            float sc = fabsf(0.4f * a);
            float wl0 = W1l[rc], wl1 = W1l[F1+rc], wl2 = W1l[2*F1+rc], wl3 = W1l[3*F1+rc];
            float wr0 = W1r[rc], wr1 = W1r[F1+rc], wr2 = W1r[2*F1+rc], wr3 = W1r[3*F1+rc];
            float bc = b1l[rc] + b1r[rc];
            int pc2 = h * 128 + newu;
            int ct = pc2 >> 5, cl2 = pc2 & 31;    // 32-channel tiles
            BpH[ct*64 + cl2] = make_uint4(packh2(sc*wl0, sc*wl1), packh2(sc*wl2, sc*wl3),
                                          packh2(sc*wr0, sc*wr1), packh2(sc*wr2, sc*wr3));
            BpH[ct*64 + 32 + cl2] = make_uint4(packh2(sc*bc, 0.f), 0u, 0u, 0u);
            if (u == 0) Bh[h] = cntPos;
            WAh[rc] = make_uint2(packh2(wl0, wl1), packh2(wl2, wl3));
            PBh[rc] = packh2(b1l[rc], bias1[rc]);
        }
        if (t < 120) {
            int i = b * 120 + t;          // pair index: h = i/60, u = i%60
            int h = i / 60, u = i - h * 60;
            int c0 = h * C1 + u, c1 = c0 + 60;
            const float4 wl0 = ((const float4*)W2l)[c0], wl1 = ((const float4*)W2l)[c1];
            const float4 wr0 = ((const float4*)W2r)[c0], wr1 = ((const float4*)W2r)[c1];
            W2P[i*2]   = make_uint4(packh2(wl0.x, wl1.x), packh2(wl0.y, wl1.y),
                                    packh2(wl0.z, wl1.z), packh2(wl0.w, wl1.w));
            W2P[i*2+1] = make_uint4(packh2(wr0.x, wr1.x), packh2(wr0.y, wr1.y),
                                    packh2(wr0.z, wr1.z), packh2(wr0.w, wr1.w));
        }
        return;
    }
    // ---- node blocks: Ps via 3-way parallel partial sums ----
    __shared__ float Pp[3][72];
    __shared__ float Ps[72];
    {
        int o = t % 72, p = t / 72;   // output o, chunk p
        if (t < 216) {
            int h = o / 9, j = o % 9;
            float acc = 0.f;
            int u0 = p * 40;
            for (int u = u0; u < u0 + 40; ++u) {
                int c = h * C1 + u;
                float a = att1[c];
                float w;
                if (j < 4)      w = W1l[j * F1 + c];
                else if (j < 8) w = W1r[(j - 4) * F1 + c];
                else            w = b1l[c] + b1r[c];
                acc = fmaf(a, w, acc);
            }
            Pp[p][o] = acc;
        }
    }
    __syncthreads();
    if (t < 72) Ps[t] = 0.6f * (Pp[0][t] + Pp[1][t] + Pp[2][t]);
    __syncthreads();
    int n = (b - 4) * 250 + t;
    if (t < 250) {
        float4 xv = ((const float4*)x)[n];
        xh[n] = make_uint2(packh2(xv.x, xv.y), packh2(xv.z, xv.w));
#pragma unroll
        for (int h = 0; h < H1; ++h) {
            const float* p = Ps + h * 9;
            Ls[n*8+h] = xv.x*p[0] + xv.y*p[1] + xv.z*p[2] + xv.w*p[3];
            Lr[n*8+h] = xv.x*p[4] + xv.y*p[5] + xv.z*p[6] + xv.w*p[7] + p[8];
        }
    }
}

// ---------------- layer-1 logits: LDS-staged 32x32x16 MFMA ----------------
// 512-thread blocks (8 waves, 256 edges; 32 edges/wave, ONE fragment set).
// A = weights (row=channel, lane&31; k=(lane>>5)*8+j: lanes<32 hold k0-7
// = [wl,wr], lanes>=32 hold k8 = bias). B = edges (col=edge, lane&31;
// lanes<32: k0-7 = [xs,xd]; lanes>=32: k8 = 1.0).
// D: col=edge (lane&31), row=(r&3)+8*(r>>2)+4*(lane>>5)  [m74/m101 verified].
// Per head: 4 MFMAs; lane halves hold complementary rows -> 1 shfl_xor(32).
// Lane (edge, g2) keeps heads 4*g2..4*g2+3 -> float4 e1 write.

__global__ __launch_bounds__(512) void logits_mfma(
        const int* __restrict__ ei, const uint2* __restrict__ xh,
        const uint4* __restrict__ BpH, const int* __restrict__ Bh,
        const float* __restrict__ Ls, const float* __restrict__ Lr,
        int* __restrict__ cnt, int* __restrict__ elist, int* __restrict__ slist,
        float* __restrict__ e1) {
    __shared__ uint4 BpL[2048];   // 32 KB
    int tid = threadIdx.x;
#pragma unroll
    for (int i = 0; i < 4; ++i) BpL[tid + i*512] = BpH[tid + i*512];
    // fused bucket fill (independent work; all threads reach the barrier)
    {
        int ef = blockIdx.x * 256 + (tid & 255);
        if (tid < 256 && ef < E_TOT) {
            int s, d;
            if (ef < N_EDGES) { s = ei[ef]; d = ei[N_EDGES + ef]; }
            else { s = ef - N_EDGES; d = s; }
            int pos = atomicAdd(&cnt[d], 1);
            int slot = d * BSTRIDE + pos;
            elist[slot] = ef;
            slist[slot] = s;
        }
    }
    __syncthreads();

    int ebase = blockIdx.x * 256 + (tid >> 6) * 32;
    if (ebase >= E_TOT) return;
    int lane = tid & 63;
    int ecol = lane & 31, g2 = lane >> 5;

    // gather: lanes<32 load edge (ebase+ecol); lanes>=32 carry the k8=1.0 row
    int s0 = 0, d0 = 0;
    AU zu;
    if (g2 == 0) {
        int er = ebase + ecol;
        if (er >= E_TOT) er = E_TOT - 1;
        if (er < N_EDGES) { s0 = ei[er]; d0 = ei[N_EDGES + er]; }
        else { s0 = er - N_EDGES; d0 = s0; }
        uint2 a = xh[s0], bb = xh[d0];
        zu.u = make_uint4(a.x, a.y, bb.x, bb.y);
    } else {
        zu.u = make_uint4(0x00003C00u, 0u, 0u, 0u);   // k8 = 1.0 (bias row)
    }
    // distribute s/d to the upper half; issue Ls/Lr gathers EARLY (float4)
    int sA = __shfl(s0, ecol, 64), dA = __shfl(d0, ecol, 64);
    float4 lsv = *(const float4*)(Ls + sA*8 + 4*g2);
    float4 lrv = *(const float4*)(Lr + dA*8 + 4*g2);

    float kk0 = 0.f, kk1 = 0.f, kk2 = 0.f, kk3 = 0.f;
#pragma unroll
    for (int h = 0; h < H1; ++h) {
        int bh = Bh[h];
        float aa = 0.f;
#pragma unroll
        for (int tt = 0; tt < 4; ++tt) {
            int ct = h * 4 + tt;
            AU wu; wu.u = BpL[ct*64 + lane];
            f32x16 z = {0.f,0.f,0.f,0.f,0.f,0.f,0.f,0.f,0.f,0.f,0.f,0.f,0.f,0.f,0.f,0.f};
            f32x16 dd = __builtin_amdgcn_mfma_f32_32x32x16_f16(wu.h, zu.h, z, 0, 0, 0);
#pragma unroll
            for (int r = 0; r < 16; ++r) {
                int row = (r & 3) + 8 * (r >> 2) + 4 * g2;
                float sel = (tt*32 + row < bh) ? 1.f : -1.f;
                aa = fmaf(sel, fabsf(dd[r]), aa);
            }
        }
        aa += __shfl_xor(aa, 32, 64);   // combine complementary row halves
        bool pk = ((h >> 2) == g2);
        if ((h & 3) == 0)      kk0 = pk ? aa : kk0;
        else if ((h & 3) == 1) kk1 = pk ? aa : kk1;
        else if ((h & 3) == 2) kk2 = pk ? aa : kk2;
        else                   kk3 = pk ? aa : kk3;
    }

    // writeout: lane (ecol, g2) writes heads 4*g2..4*g2+3 for edge ebase+ecol
    {
        int e0 = ebase + ecol;
        if (e0 < E_TOT) {
            float4 o = make_float4(__expf(lsv.x + lrv.x + kk0),
                                   __expf(lsv.y + lrv.y + kk1),
                                   __expf(lsv.z + lrv.z + kk2),
                                   __expf(lsv.w + lrv.w + kk3));
            *(float4*)(e1 + (size_t)e0*8 + 4*g2) = o;
        }
    }
}

// ---------------- layer-1 agg + f16 expand + relu + layer-2 transform ----------------
// 16 lanes per node; bucket CSR (beg = node*BSTRIDE, len = cnt[node])

#define AGG(hi, wv) { float W_ = (wv); ssum[hi] += W_; ag[hi].x += W_*xv.x; ag[hi].y += W_*xv.y; ag[hi].z += W_*xv.z; ag[hi].w += W_*xv.w; }

__global__ __launch_bounds__(256) void fused_agg1(
        const int* __restrict__ cnt, const int* __restrict__ elist,
        const int* __restrict__ slist,
        const float* __restrict__ e1, const float* __restrict__ x,
        const uint2* __restrict__ WAh, const unsigned* __restrict__ PBh,
        const uint4* __restrict__ W2P,
        const float* __restrict__ b2l, const float* __restrict__ b2r,
        float* __restrict__ xl2, float* __restrict__ xr2) {
    int tid = threadIdx.x;
    int node = blockIdx.x * 16 + (tid >> 4);
    int l = tid & 15;
    int beg = node * BSTRIDE, end = beg + cnt[node];

    float ssum[H1]; float4 ag[H1];
#pragma unroll
    for (int h = 0; h < H1; ++h) { ssum[h] = 0.f; ag[h] = make_float4(0.f,0.f,0.f,0.f); }

    for (int i = beg + l; i < end; i += 16) {
        int e = elist[i];
        const float4* p = (const float4*)(e1 + (size_t)e * 8);
        float4 wa = p[0], wb = p[1];
        float4 xv = ((const float4*)x)[slist[i]];
        AGG(0, wa.x) AGG(1, wa.y) AGG(2, wa.z) AGG(3, wa.w)
        AGG(4, wb.x) AGG(5, wb.y) AGG(6, wb.z) AGG(7, wb.w)
    }
#pragma unroll
    for (int off = 8; off; off >>= 1) {
#pragma unroll
        for (int h = 0; h < H1; ++h) {
            ssum[h] += __shfl_xor(ssum[h], off, 64);
            ag[h].x += __shfl_xor(ag[h].x, off, 64);
            ag[h].y += __shfl_xor(ag[h].y, off, 64);
            ag[h].z += __shfl_xor(ag[h].z, off, 64);
            ag[h].w += __shfl_xor(ag[h].w, off, 64);
        }
    }
    unsigned agA[H1], agB[H1], sg[H1];
#pragma unroll
    for (int h = 0; h < H1; ++h) {
        float inv = 1.f / (ssum[h] + 1e-16f);
        agA[h] = packh2(ag[h].x * inv, ag[h].y * inv);
        agB[h] = packh2(ag[h].z * inv, ag[h].w * inv);
        sg[h]  = packh2(ssum[h] * inv, 1.f);
    }

    float al0=0, al1=0, al2=0, al3=0, ar0=0, ar1=0, ar2=0, ar3=0;
#pragma unroll
    for (int h = 0; h < H1; ++h) {
        h2 ga = toh2(agA[h]), gb = toh2(agB[h]), gs = toh2(sg[h]);
#pragma unroll
        for (int j = 0; j < 4; ++j) {
            int u = l + 16*j;
            if (u < 60) {
                int c0 = h*C1 + u;
                uint2 wa0 = WAh[c0];      unsigned pb0 = PBh[c0];
                uint2 wa1 = WAh[c0 + 60]; unsigned pb1 = PBh[c0 + 60];
                float f0 = FDOT2(gs, toh2(pb0), 0.f);
                f0 = FDOT2(ga, toh2(wa0.x), f0);
                f0 = FDOT2(gb, toh2(wa0.y), f0);
                f0 = fmaxf(f0, 0.f);
                float f1 = FDOT2(gs, toh2(pb1), 0.f);
                f1 = FDOT2(ga, toh2(wa1.x), f1);
                f1 = FDOT2(gb, toh2(wa1.y), f1);
                f1 = fmaxf(f1, 0.f);
                h2 hp = toh2(packh2(f0, f1));
                int pi = (h*60 + u) * 2;
                uint4 wA = W2P[pi], wB = W2P[pi + 1];
                al0 = FDOT2(hp, toh2(wA.x), al0); al1 = FDOT2(hp, toh2(wA.y), al1);
                al2 = FDOT2(hp, toh2(wA.z), al2); al3 = FDOT2(hp, toh2(wA.w), al3);
                ar0 = FDOT2(hp, toh2(wB.x), ar0); ar1 = FDOT2(hp, toh2(wB.y), ar1);
                ar2 = FDOT2(hp, toh2(wB.z), ar2); ar3 = FDOT2(hp, toh2(wB.w), ar3);
            }
        }
    }
#pragma unroll
    for (int off = 8; off; off >>= 1) {
        al0 += __shfl_xor(al0, off, 64); al1 += __shfl_xor(al1, off, 64);
        al2 += __shfl_xor(al2, off, 64); al3 += __shfl_xor(al3, off, 64);
        ar0 += __shfl_xor(ar0, off, 64); ar1 += __shfl_xor(ar1, off, 64);
        ar2 += __shfl_xor(ar2, off, 64); ar3 += __shfl_xor(ar3, off, 64);
    }
    if (l == 0) {
        ((float4*)xl2)[node] = make_float4(al0 + b2l[0], al1 + b2l[1], al2 + b2l[2], al3 + b2l[3]);
        ((float4*)xr2)[node] = make_float4(ar0 + b2r[0], ar1 + b2r[1], ar2 + b2r[2], ar3 + b2r[3]);
    }
}

// ---------------- layer-2 fused attention ----------------

__global__ __launch_bounds__(256) void attn2(
        const int* __restrict__ cnt, const int* __restrict__ slist,
        const float* __restrict__ xl2, const float* __restrict__ xr2,
        const float* __restrict__ att2, const float* __restrict__ bias2,
        float* __restrict__ out) {
    int tid = threadIdx.x;
    int node = blockIdx.x * 16 + (tid >> 4);
    int l = tid & 15;
    int beg = node * BSTRIDE, end = beg + cnt[node];
    float4 xr = ((const float4*)xr2)[node];
    float a0 = att2[0], a1 = att2[1], a2 = att2[2], a3 = att2[3];

    float ssum = 0.f;
    float4 acc = make_float4(0.f, 0.f, 0.f, 0.f);
    for (int i = beg + l; i < end; i += 16) {
        float4 v = ((const float4*)xl2)[slist[i]];
        float lg = a0*lrelu(v.x + xr.x) + a1*lrelu(v.y + xr.y)
                 + a2*lrelu(v.z + xr.z) + a3*lrelu(v.w + xr.w);
        float w = __expf(lg);
        ssum += w;
        acc.x += w*v.x; acc.y += w*v.y; acc.z += w*v.z; acc.w += w*v.w;
    }
#pragma unroll
    for (int off = 8; off; off >>= 1) {
        ssum  += __shfl_xor(ssum,  off, 64);
        acc.x += __shfl_xor(acc.x, off, 64);
        acc.y += __shfl_xor(acc.y, off, 64);
        acc.z += __shfl_xor(acc.z, off, 64);
        acc.w += __shfl_xor(acc.w, off, 64);
    }
    if (l == 0) {
        float inv = 1.f / (ssum + 1e-16f);
        ((float4*)out)[node] = make_float4(acc.x*inv + bias2[0], acc.y*inv + bias2[1],
                                           acc.z*inv + bias2[2], acc.w*inv + bias2[3]);
    }
}

extern "C" void kernel_launch(void* const* d_in, const int* in_sizes, int n_in,
                              void* d_out, int out_size, void* d_ws, size_t ws_size,
                              hipStream_t stream) {
    const float* x     = (const float*)d_in[0];
    const int*   ei    = (const int*)  d_in[1];
    const float* W1l   = (const float*)d_in[2];
    const float* W1r   = (const float*)d_in[3];
    const float* b1l   = (const float*)d_in[4];
    const float* b1r   = (const float*)d_in[5];
    const float* att1  = (const float*)d_in[6];
    const float* bias1 = (const float*)d_in[7];
    const float* W2l   = (const float*)d_in[8];
    const float* W2r   = (const float*)d_in[9];
    const float* b2l   = (const float*)d_in[10];
    const float* b2r   = (const float*)d_in[11];
    const float* att2  = (const float*)d_in[12];
    const float* bias2 = (const float*)d_in[13];
    float* out = (float*)d_out;

    // workspace carve-up (segments 16B-aligned)
    float* e1   = (float*)d_ws;                   // E_TOT*8 = 1,360,000 f (EDGE order)
    float* Ls   = e1 + (size_t)E_TOT * 8;         // 80,000
    float* Lr   = Ls + 80000;                     // 80,000
    float* xl2  = Lr + 80000;                     // 40,000
    float* xr2  = xl2 + 40000;                    // 40,000
    unsigned* BpHu = (unsigned*)(xr2 + 40000);    // 8,192 (uint4[2048])
    int* Bh     = (int*)(BpHu + 8192);            // 16 (8 used)
    unsigned* WAhu = (unsigned*)(Bh + 16);        // 1,920 (uint2[960])
    unsigned* W2Pu = WAhu + 1920;                 // 7,680 (uint4[1920])
    unsigned* PBhu = W2Pu + 7680;                 // 960
    unsigned* xhu  = PBhu + 960;                  // 20,000 (uint2[10000])
    int* cnt    = (int*)(xhu + 20000);            // 10,000
    int* elist  = cnt + 10000;                    // N_NODES*BSTRIDE = 640,000
    int* slist  = elist + N_NODES * BSTRIDE;      // 640,000

    const int B = 256;

    prep<<<84, B, 0, stream>>>(
        x, W1l, W1r, b1l, b1r, att1, bias1, W2l, W2r,
        (uint4*)BpHu, Bh, (uint2*)WAhu, PBhu, (uint4*)W2Pu,
        (uint2*)xhu, Ls, Lr, cnt);

    logits_mfma<<<(E_TOT + 255) / 256, 512, 0, stream>>>(
        ei, (const uint2*)xhu, (const uint4*)BpHu, Bh, Ls, Lr,
        cnt, elist, slist, e1);
    fused_agg1<<<N_NODES / 16, B, 0, stream>>>(
        cnt, elist, slist, e1, x, (const uint2*)WAhu, PBhu, (const uint4*)W2Pu,
        b2l, b2r, xl2, xr2);
    attn2<<<N_NODES / 16, B, 0, stream>>>(cnt, slist, xl2, xr2, att2, bias2, out);
}

// Round 21
// 66.036 us; speedup vs baseline: 4.9483x; 1.0450x over previous
//
#include <hip/hip_runtime.h>

#define N_NODES 10000
#define N_EDGES 160000
#define E_TOT   170000   // + self loops
#define H1      8
#define C1      120
#define F1      960      // H1*C1
#define BSTRIDE 64       // bucket slots per node (max in-degree ~45 << 64)

typedef _Float16 h2 __attribute__((ext_vector_type(2)));
typedef _Float16 f16x8 __attribute__((ext_vector_type(8)));
typedef float f32x4 __attribute__((ext_vector_type(4)));
typedef float f32x16 __attribute__((ext_vector_type(16)));
union H2U { unsigned u; h2 h; };
union AU  { uint4 u; f16x8 h; };

#if defined(__has_builtin)
#if __has_builtin(__builtin_amdgcn_fdot2)
#define FDOT2(a,b,c) __builtin_amdgcn_fdot2((a),(b),(c),false)
#endif
#endif
#ifndef FDOT2
#define FDOT2(a,b,c) ((float)(a)[0]*(float)(b)[0] + (float)(a)[1]*(float)(b)[1] + (c))
#endif

__device__ __forceinline__ float lrelu(float v) { return fmaxf(v, 0.2f * v); }
__device__ __forceinline__ unsigned packh2(float a, float b) {
    H2U u; u.h = (h2){(_Float16)a, (_Float16)b}; return u.u;
}
__device__ __forceinline__ h2 toh2(unsigned v) { H2U u; u.u = v; return u.h; }

// ---------------- fused prep ----------------
// blocks 0..3: zero own Bp range; t<240: |0.4*att|-folded sorted weight table
//   in 32x32-tile layout (pc2 = h*128+newu, ct = pc2>>5, cl = pc2&31);
//   Bh[h] = #pos; WAh/PBh (orig order); W2P (t<120).
// blocks 4..43: Ps 3-way-parallel; 250 nodes each: xh pack, Ls, Lr.
// blocks 44..83: zero cnt.
__global__ __launch_bounds__(256) void prep(
        const float* __restrict__ x,
        const float* __restrict__ W1l, const float* __restrict__ W1r,
        const float* __restrict__ b1l, const float* __restrict__ b1r,
        const float* __restrict__ att1, const float* __restrict__ bias1,
        const float* __restrict__ W2l, const float* __restrict__ W2r,
        uint4* __restrict__ BpH, int* __restrict__ Bh,
        uint2* __restrict__ WAh, unsigned* __restrict__ PBh,
        uint4* __restrict__ W2P,
        uint2* __restrict__ xh, float* __restrict__ Ls, float* __restrict__ Lr,
        int* __restrict__ cnt) {
    int b = blockIdx.x, t = threadIdx.x;
    if (b >= 44) {
        int i = (b - 44) * 256 + t;
        if (i < N_NODES) cnt[i] = 0;
        return;
    }
    if (b < 4) {
        BpH[b*512 + t]       = make_uint4(0u,0u,0u,0u);
        BpH[b*512 + 256 + t] = make_uint4(0u,0u,0u,0u);
        __syncthreads();
        if (t < 240) {
            int rc = b * 240 + t;
            int h = rc / C1, u = rc - h * C1;
            float a = att1[rc];
            int cntPos = 0, rankB = 0;
            for (int v = 0; v < C1; ++v) {
                bool pos = att1[h*C1 + v] > 0.f;
                cntPos += pos ? 1 : 0;
                rankB  += (v < u && pos) ? 1 : 0;
            }
            int newu = (a > 0.f) ? rankB : (cntPos + (u - rankB));
            float sc = fabsf(0.4f * a);
            float wl0 = W1l[rc], wl1 = W1l[F1+rc], wl2 = W1l[2*F1+rc], wl3 = W1l[3*F1+rc];
            float wr0 = W1r[rc], wr1 = W1r[F1+rc], wr2 = W1r[2*F1+rc], wr3 = W1r[3*F1+rc];
            float bc = b1l[rc] + b1r[rc];
            int pc2 = h * 128 + newu;
            int ct = pc2 >> 5, cl2 = pc2 & 31;    // 32-channel tiles
            BpH[ct*64 + cl2] = make_uint4(packh2(sc*wl0, sc*wl1), packh2(sc*wl2, sc*wl3),
                                          packh2(sc*wr0, sc*wr1), packh2(sc*wr2, sc*wr3));
            BpH[ct*64 + 32 + cl2] = make_uint4(packh2(sc*bc, 0.f), 0u, 0u, 0u);
            if (u == 0) Bh[h] = cntPos;
            WAh[rc] = make_uint2(packh2(wl0, wl1), packh2(wl2, wl3));
            PBh[rc] = packh2(b1l[rc], bias1[rc]);
        }
        if (t < 120) {
            int i = b * 120 + t;          // pair index: h = i/60, u = i%60
            int h = i / 60, u = i - h * 60;
            int c0 = h * C1 + u, c1 = c0 + 60;
            const float4 wl0 = ((const float4*)W2l)[c0], wl1 = ((const float4*)W2l)[c1];
            const float4 wr0 = ((const float4*)W2r)[c0], wr1 = ((const float4*)W2r)[c1];
            W2P[i*2]   = make_uint4(packh2(wl0.x, wl1.x), packh2(wl0.y, wl1.y),
                                    packh2(wl0.z, wl1.z), packh2(wl0.w, wl1.w));
            W2P[i*2+1] = make_uint4(packh2(wr0.x, wr1.x), packh2(wr0.y, wr1.y),
                                    packh2(wr0.z, wr1.z), packh2(wr0.w, wr1.w));
        }
        return;
    }
    __shared__ float Pp[3][72];
    __shared__ float Ps[72];
    {
        int o = t % 72, p = t / 72;
        if (t < 216) {
            int h = o / 9, j = o % 9;
            float acc = 0.f;
            int u0 = p * 40;
            for (int u = u0; u < u0 + 40; ++u) {
                int c = h * C1 + u;
                float a = att1[c];
                float w;
                if (j < 4)      w = W1l[j * F1 + c];
                else if (j < 8) w = W1r[(j - 4) * F1 + c];
                else            w = b1l[c] + b1r[c];
                acc = fmaf(a, w, acc);
            }
            Pp[p][o] = acc;
        }
    }
    __syncthreads();
    if (t < 72) Ps[t] = 0.6f * (Pp[0][t] + Pp[1][t] + Pp[2][t]);
    __syncthreads();
    int n = (b - 4) * 250 + t;
    if (t < 250) {
        float4 xv = ((const float4*)x)[n];
        xh[n] = make_uint2(packh2(xv.x, xv.y), packh2(xv.z, xv.w));
#pragma unroll
        for (int h = 0; h < H1; ++h) {
            const float* p = Ps + h * 9;
            Ls[n*8+h] = xv.x*p[0] + xv.y*p[1] + xv.z*p[2] + xv.w*p[3];
            Lr[n*8+h] = xv.x*p[4] + xv.y*p[5] + xv.z*p[6] + xv.w*p[7] + p[8];
        }
    }
}

// ---------------- layer-1 logits: LDS-staged 32x32x16 MFMA, bucket-ordered e1 ----------------
// 512-thread blocks (8 waves, 256 edges; 32 edges/wave). Bucket fill stores
// each edge's slot in LDS (same-block edges) -> writeout scatters e1 to the
// bucket slot, so fused_agg1 reads e1 CONTIGUOUSLY and elist is eliminated.

__global__ __launch_bounds__(512) void logits_mfma(
        const int* __restrict__ ei, const uint2* __restrict__ xh,
        const uint4* __restrict__ BpH, const int* __restrict__ Bh,
        const float* __restrict__ Ls, const float* __restrict__ Lr,
        int* __restrict__ cnt, int* __restrict__ slist,
        float* __restrict__ e1) {
    __shared__ uint4 BpL[2048];   // 32 KB
    __shared__ int eposL[256];    // bucket slot per block-local edge
    int tid = threadIdx.x;
#pragma unroll
    for (int i = 0; i < 4; ++i) BpL[tid + i*512] = BpH[tid + i*512];
    // fused bucket fill (same 256 edges this block's waves compute)
    {
        int lidx = tid & 255;
        int ef = blockIdx.x * 256 + lidx;
        if (tid < 256 && ef < E_TOT) {
            int s, d;
            if (ef < N_EDGES) { s = ei[ef]; d = ei[N_EDGES + ef]; }
            else { s = ef - N_EDGES; d = s; }
            int pos = atomicAdd(&cnt[d], 1);
            int slot = d * BSTRIDE + pos;
            slist[slot] = s;
            eposL[lidx] = slot;
        }
    }
    __syncthreads();

    int ebase = blockIdx.x * 256 + (tid >> 6) * 32;
    if (ebase >= E_TOT) return;
    int lane = tid & 63;
    int ecol = lane & 31, g2 = lane >> 5;

    // gather: lanes<32 load edge (ebase+ecol); lanes>=32 carry the k8=1.0 row
    int s0 = 0, d0 = 0;
    AU zu;
    if (g2 == 0) {
        int er = ebase + ecol;
        if (er >= E_TOT) er = E_TOT - 1;
        if (er < N_EDGES) { s0 = ei[er]; d0 = ei[N_EDGES + er]; }
        else { s0 = er - N_EDGES; d0 = s0; }
        uint2 a = xh[s0], bb = xh[d0];
        zu.u = make_uint4(a.x, a.y, bb.x, bb.y);
    } else {
        zu.u = make_uint4(0x00003C00u, 0u, 0u, 0u);   // k8 = 1.0 (bias row)
    }
    int sA = __shfl(s0, ecol, 64), dA = __shfl(d0, ecol, 64);
    float4 lsv = *(const float4*)(Ls + sA*8 + 4*g2);
    float4 lrv = *(const float4*)(Lr + dA*8 + 4*g2);

    float kk0 = 0.f, kk1 = 0.f, kk2 = 0.f, kk3 = 0.f;
#pragma unroll
    for (int h = 0; h < H1; ++h) {
        int bh = Bh[h];
        float aa = 0.f;
#pragma unroll
        for (int tt = 0; tt < 4; ++tt) {
            int ct = h * 4 + tt;
            AU wu; wu.u = BpL[ct*64 + lane];
            f32x16 z = {0.f,0.f,0.f,0.f,0.f,0.f,0.f,0.f,0.f,0.f,0.f,0.f,0.f,0.f,0.f,0.f};
            f32x16 dd = __builtin_amdgcn_mfma_f32_32x32x16_f16(wu.h, zu.h, z, 0, 0, 0);
#pragma unroll
            for (int r = 0; r < 16; ++r) {
                int row = (r & 3) + 8 * (r >> 2) + 4 * g2;
                float sel = (tt*32 + row < bh) ? 1.f : -1.f;
                aa = fmaf(sel, fabsf(dd[r]), aa);
            }
        }
        aa += __shfl_xor(aa, 32, 64);   // combine complementary row halves
        bool pk = ((h >> 2) == g2);
        if ((h & 3) == 0)      kk0 = pk ? aa : kk0;
        else if ((h & 3) == 1) kk1 = pk ? aa : kk1;
        else if ((h & 3) == 2) kk2 = pk ? aa : kk2;
        else                   kk3 = pk ? aa : kk3;
    }

    // writeout to bucket slot (lane (ecol,g2) writes heads 4*g2..4*g2+3)
    {
        int e0 = ebase + ecol;
        if (e0 < E_TOT) {
            int slot = eposL[(tid >> 6) * 32 + ecol];
            float4 o = make_float4(__expf(lsv.x + lrv.x + kk0),
                                   __expf(lsv.y + lrv.y + kk1),
                                   __expf(lsv.z + lrv.z + kk2),
                                   __expf(lsv.w + lrv.w + kk3));
            *(float4*)(e1 + (size_t)slot*8 + 4*g2) = o;
        }
    }
}

// ---------------- layer-1 agg + f16 expand + relu + layer-2 transform ----------------
// 16 lanes per node; bucket CSR; e1 read CONTIGUOUSLY (bucket order)

#define AGG(hi, wv) { float W_ = (wv); ssum[hi] += W_; ag[hi].x += W_*xv.x; ag[hi].y += W_*xv.y; ag[hi].z += W_*xv.z; ag[hi].w += W_*xv.w; }

__global__ __launch_bounds__(256) void fused_agg1(
        const int* __restrict__ cnt, const int* __restrict__ slist,
        const float* __restrict__ e1, const float* __restrict__ x,
        const uint2* __restrict__ WAh, const unsigned* __restrict__ PBh,
        const uint4* __restrict__ W2P,
        const float* __restrict__ b2l, const float* __restrict__ b2r,
        float* __restrict__ xl2, float* __restrict__ xr2) {
    int tid = threadIdx.x;
    int node = blockIdx.x * 16 + (tid >> 4);
    int l = tid & 15;
    int beg = node * BSTRIDE, end = beg + cnt[node];

    float ssum[H1]; float4 ag[H1];
#pragma unroll
    for (int h = 0; h < H1; ++h) { ssum[h] = 0.f; ag[h] = make_float4(0.f,0.f,0.f,0.f); }

    for (int i = beg + l; i < end; i += 16) {
        const float4* p = (const float4*)(e1 + (size_t)i * 8);
        float4 wa = p[0], wb = p[1];
        float4 xv = ((const float4*)x)[slist[i]];
        AGG(0, wa.x) AGG(1, wa.y) AGG(2, wa.z) AGG(3, wa.w)
        AGG(4, wb.x) AGG(5, wb.y) AGG(6, wb.z) AGG(7, wb.w)
    }
#pragma unroll
    for (int off = 8; off; off >>= 1) {
#pragma unroll
        for (int h = 0; h < H1; ++h) {
            ssum[h] += __shfl_xor(ssum[h], off, 64);
            ag[h].x += __shfl_xor(ag[h].x, off, 64);
            ag[h].y += __shfl_xor(ag[h].y, off, 64);
            ag[h].z += __shfl_xor(ag[h].z, off, 64);
            ag[h].w += __shfl_xor(ag[h].w, off, 64);
        }
    }
    unsigned agA[H1], agB[H1], sg[H1];
#pragma unroll
    for (int h = 0; h < H1; ++h) {
        float inv = 1.f / (ssum[h] + 1e-16f);
        agA[h] = packh2(ag[h].x * inv, ag[h].y * inv);
        agB[h] = packh2(ag[h].z * inv, ag[h].w * inv);
        sg[h]  = packh2(ssum[h] * inv, 1.f);
    }

    float al0=0, al1=0, al2=0, al3=0, ar0=0, ar1=0, ar2=0, ar3=0;
#pragma unroll
    for (int h = 0; h < H1; ++h) {
        h2 ga = toh2(agA[h]), gb = toh2(agB[h]), gs = toh2(sg[h]);
#pragma unroll
        for (int j = 0; j < 4; ++j) {
            int u = l + 16*j;
            if (u < 60) {
                int c0 = h*C1 + u;
                uint2 wa0 = WAh[c0];      unsigned pb0 = PBh[c0];
                uint2 wa1 = WAh[c0 + 60]; unsigned pb1 = PBh[c0 + 60];
                float f0 = FDOT2(gs, toh2(pb0), 0.f);
                f0 = FDOT2(ga, toh2(wa0.x), f0);
                f0 = FDOT2(gb, toh2(wa0.y), f0);
                f0 = fmaxf(f0, 0.f);
                float f1 = FDOT2(gs, toh2(pb1), 0.f);
                f1 = FDOT2(ga, toh2(wa1.x), f1);
                f1 = FDOT2(gb, toh2(wa1.y), f1);
                f1 = fmaxf(f1, 0.f);
                h2 hp = toh2(packh2(f0, f1));
                int pi = (h*60 + u) * 2;
                uint4 wA = W2P[pi], wB = W2P[pi + 1];
                al0 = FDOT2(hp, toh2(wA.x), al0); al1 = FDOT2(hp, toh2(wA.y), al1);
                al2 = FDOT2(hp, toh2(wA.z), al2); al3 = FDOT2(hp, toh2(wA.w), al3);
                ar0 = FDOT2(hp, toh2(wB.x), ar0); ar1 = FDOT2(hp, toh2(wB.y), ar1);
                ar2 = FDOT2(hp, toh2(wB.z), ar2); ar3 = FDOT2(hp, toh2(wB.w), ar3);
            }
        }
    }
#pragma unroll
    for (int off = 8; off; off >>= 1) {
        al0 += __shfl_xor(al0, off, 64); al1 += __shfl_xor(al1, off, 64);
        al2 += __shfl_xor(al2, off, 64); al3 += __shfl_xor(al3, off, 64);
        ar0 += __shfl_xor(ar0, off, 64); ar1 += __shfl_xor(ar1, off, 64);
        ar2 += __shfl_xor(ar2, off, 64); ar3 += __shfl_xor(ar3, off, 64);
    }
    if (l == 0) {
        ((float4*)xl2)[node] = make_float4(al0 + b2l[0], al1 + b2l[1], al2 + b2l[2], al3 + b2l[3]);
        ((float4*)xr2)[node] = make_float4(ar0 + b2r[0], ar1 + b2r[1], ar2 + b2r[2], ar3 + b2r[3]);
    }
}

// ---------------- layer-2 fused attention ----------------

__global__ __launch_bounds__(256) void attn2(
        const int* __restrict__ cnt, const int* __restrict__ slist,
        const float* __restrict__ xl2, const float* __restrict__ xr2,
        const float* __restrict__ att2, const float* __restrict__ bias2,
        float* __restrict__ out) {
    int tid = threadIdx.x;
    int node = blockIdx.x * 16 + (tid >> 4);
    int l = tid & 15;
    int beg = node * BSTRIDE, end = beg + cnt[node];
    float4 xr = ((const float4*)xr2)[node];
    float a0 = att2[0], a1 = att2[1], a2 = att2[2], a3 = att2[3];

    float ssum = 0.f;
    float4 acc = make_float4(0.f, 0.f, 0.f, 0.f);
    for (int i = beg + l; i < end; i += 16) {
        float4 v = ((const float4*)xl2)[slist[i]];
        float lg = a0*lrelu(v.x + xr.x) + a1*lrelu(v.y + xr.y)
                 + a2*lrelu(v.z + xr.z) + a3*lrelu(v.w + xr.w);
        float w = __expf(lg);
        ssum += w;
        acc.x += w*v.x; acc.y += w*v.y; acc.z += w*v.z; acc.w += w*v.w;
    }
#pragma unroll
    for (int off = 8; off; off >>= 1) {
        ssum  += __shfl_xor(ssum,  off, 64);
        acc.x += __shfl_xor(acc.x, off, 64);
        acc.y += __shfl_xor(acc.y, off, 64);
        acc.z += __shfl_xor(acc.z, off, 64);
        acc.w += __shfl_xor(acc.w, off, 64);
    }
    if (l == 0) {
        float inv = 1.f / (ssum + 1e-16f);
        ((float4*)out)[node] = make_float4(acc.x*inv + bias2[0], acc.y*inv + bias2[1],
                                           acc.z*inv + bias2[2], acc.w*inv + bias2[3]);
    }
}

extern "C" void kernel_launch(void* const* d_in, const int* in_sizes, int n_in,
                              void* d_out, int out_size, void* d_ws, size_t ws_size,
                              hipStream_t stream) {
    const float* x     = (const float*)d_in[0];
    const int*   ei    = (const int*)  d_in[1];
    const float* W1l   = (const float*)d_in[2];
    const float* W1r   = (const float*)d_in[3];
    const float* b1l   = (const float*)d_in[4];
    const float* b1r   = (const float*)d_in[5];
    const float* att1  = (const float*)d_in[6];
    const float* bias1 = (const float*)d_in[7];
    const float* W2l   = (const float*)d_in[8];
    const float* W2r   = (const float*)d_in[9];
    const float* b2l   = (const float*)d_in[10];
    const float* b2r   = (const float*)d_in[11];
    const float* att2  = (const float*)d_in[12];
    const float* bias2 = (const float*)d_in[13];
    float* out = (float*)d_out;

    // workspace carve-up (segments 16B-aligned)
    float* e1   = (float*)d_ws;                   // N_NODES*BSTRIDE*8 = 5,120,000 f (BUCKET order)
    float* Ls   = e1 + (size_t)N_NODES * BSTRIDE * 8;  // 80,000
    float* Lr   = Ls + 80000;                     // 80,000
    float* xl2  = Lr + 80000;                     // 40,000
    float* xr2  = xl2 + 40000;                    // 40,000
    unsigned* BpHu = (unsigned*)(xr2 + 40000);    // 8,192 (uint4[2048])
    int* Bh     = (int*)(BpHu + 8192);            // 16 (8 used)
    unsigned* WAhu = (unsigned*)(Bh + 16);        // 1,920 (uint2[960])
    unsigned* W2Pu = WAhu + 1920;                 // 7,680 (uint4[1920])
    unsigned* PBhu = W2Pu + 7680;                 // 960
    unsigned* xhu  = PBhu + 960;                  // 20,000 (uint2[10000])
    int* cnt    = (int*)(xhu + 20000);            // 10,000
    int* slist  = cnt + 10000;                    // N_NODES*BSTRIDE = 640,000

    const int B = 256;

    prep<<<84, B, 0, stream>>>(
        x, W1l, W1r, b1l, b1r, att1, bias1, W2l, W2r,
        (uint4*)BpHu, Bh, (uint2*)WAhu, PBhu, (uint4*)W2Pu,
        (uint2*)xhu, Ls, Lr, cnt);

    logits_mfma<<<(E_TOT + 255) / 256, 512, 0, stream>>>(
        ei, (const uint2*)xhu, (const uint4*)BpHu, Bh, Ls, Lr,
        cnt, slist, e1);
    fused_agg1<<<N_NODES / 16, B, 0, stream>>>(
        cnt, slist, e1, x, (const uint2*)WAhu, PBhu, (const uint4*)W2Pu,
        b2l, b2r, xl2, xr2);
    attn2<<<N_NODES / 16, B, 0, stream>>>(cnt, slist, xl2, xr2, att2, bias2, out);
}